// Round 7
// baseline (891.791 us; speedup 1.0000x reference)
//
#include <hip/hip_runtime.h>

#define DI __device__ __forceinline__

constexpr int Bc = 4, Tc = 4096, Ic = 1024, Ec = 16, Kc = 512, Jc = 1024;

typedef __attribute__((ext_vector_type(8))) short short8;
typedef __attribute__((ext_vector_type(4))) float floatx4;

// pack two fp32 -> two bf16 (round-half-up): low16 = bf16(a), high16 = bf16(b)
DI unsigned pack2_bf16(float a, float b) {
  union { float f; unsigned u; } ua, ub;
  ua.f = a; ub.f = b;
  const unsigned x = ua.u + 0x8000u;
  const unsigned y = ub.u + 0x8000u;
#if __has_builtin(__builtin_amdgcn_perm)
  return __builtin_amdgcn_perm(y, x, 0x07060302u);
#else
  return (x >> 16) | (y & 0xFFFF0000u);
#endif
}

DI void async_load16(const void* g, void* lds) {
  __builtin_amdgcn_global_load_lds((const __attribute__((address_space(1))) void*)g,
                                   (__attribute__((address_space(3))) void*)lds,
                                   16, 0, 0);
}

// ---------------------------------------------------------------------------
// prep v3 (measured ~80us): sync-free, LDS-free.
// Blocks [0,4096): X gather+cast into ROW-MAJOR Xg[32768][1024] bf16.
// Blocks [4096,6144): W transpose+cast into Wt[(e*8+jt)*32+kk][128n][32i].
__global__ __launch_bounds__(256) void prep(const float* __restrict__ X,
                                            const int* __restrict__ ind,
                                            const float* __restrict__ W,
                                            unsigned short* __restrict__ Xg,
                                            unsigned short* __restrict__ Wt) {
  const int t = threadIdx.x;
  const int bx = blockIdx.x;

  if (bx < 4096) {
    // ---- X part: 32768 rows x 32 chunks; 8 rows per block ----
    const int r8 = t >> 5;              // row within block
    const int c  = t & 31;              // 32-float chunk within row
    const int R  = bx * 8 + r8;         // gathered-row id
    const int b  = R >> 13;             // E*K = 8192 rows per batch
    const int xr = ind[R];
    const float* src = X + ((size_t)(b * Tc + xr)) * Ic + c * 32;
    unsigned u[16];
#pragma unroll
    for (int q = 0; q < 8; ++q) {
      const float4 v = *(const float4*)(src + q * 4);
      u[2 * q]     = pack2_bf16(v.x, v.y);
      u[2 * q + 1] = pack2_bf16(v.z, v.w);
    }
    unsigned short* dst = Xg + (size_t)R * Ic + c * 32;
#pragma unroll
    for (int q = 0; q < 4; ++q) *(uint4*)(dst + q * 8) = *(uint4*)&u[4 * q];
  } else {
    // ---- W part: 524,288 items = 4096 grps x 128 n ----
    const int item = (bx - 4096) * 256 + t;
    const int n   = item & 127;
    const int grp = item >> 7;          // (e*8+jt)*32 + kk
    const int kk  = grp & 31;
    const int jt  = (grp >> 5) & 7;
    const int e   = grp >> 8;
    const float* src = W + ((size_t)(e * Ic + kk * 32)) * Jc + jt * 128 + n;
    unsigned u[16];
#pragma unroll
    for (int q = 0; q < 16; ++q) {
      const float a  = src[(size_t)(2 * q) * Jc];
      const float c2 = src[(size_t)(2 * q + 1) * Jc];
      u[q] = pack2_bf16(a, c2);
    }
    unsigned short* dst = Wt + (size_t)grp * 4096 + n * 32;
#pragma unroll
    for (int q = 0; q < 4; ++q) *(uint4*)(dst + q * 8) = *(uint4*)&u[4 * q];
  }
}

// ---------------------------------------------------------------------------
// moe_gemm v3b: 256x256 tile, BK=32, 8 waves, RING-2 (64KB LDS => 2 blocks/CU,
// all 512 blocks co-resident). One barrier per K-tile; stage(kt+1) issued
// after the barrier (race-free: all waves' tile-(kt-1) reads completed before
// their MFMAs, hence before the barrier); counted vmcnt(4) steady-state,
// vmcnt(0) on the LAST tile (only 4 loads outstanding there — vmcnt(4) would
// NOT wait; this was a latent tail race). No sched fences in compute so the
// compiler interleaves ds_read_b128 with MFMA. Same MFMA order => bit-identical
// numerics. GRID MUST BE 512.
__global__ __launch_bounds__(512, 4) void moe_gemm(const unsigned short* __restrict__ Xg,
                                                   const unsigned short* __restrict__ Wt,
                                                   float* __restrict__ Y) {
  __shared__ __align__(16) unsigned short As[2 * 8192];   // 2 bufs x 16 KB
  __shared__ __align__(16) unsigned short Bs[2 * 8192];   // 2 bufs x 16 KB

  const int bid   = blockIdx.x;                 // 512 blocks
  const int lg    = (bid & 7) * 64 + (bid >> 3);
  const int e     = lg >> 5;
  const int inner = lg & 31;
  const int b     = inner >> 3;
  const int mt    = (inner >> 2) & 1;
  const int nt    = inner & 3;

  const int t = threadIdx.x;
  const int w = t >> 6;
  const int l = t & 63;
  const int lrow = l & 15;
  const int q    = l >> 4;

  const int tt0 = b * 64 + e * 4 + mt * 2;      // first 128-row tile of A
  const int jg0 = e * 8 + nt * 2;               // first 128-col Wt group

  // staging lane -> (row sr, 16B piece sc); source piece pre-swizzled so LDS
  // pos p holds data of pos p^((sr>>1)&3); read side applies the same XOR.
  const int sr = t >> 2, sc = t & 3;
  const int scs = (sc ^ ((sr >> 1) & 3)) << 3;

  const unsigned short* aC = Xg + ((size_t)(tt0 * 128 + sr)) * (size_t)Ic + scs;
  const size_t lsrc = (size_t)sr * 32 + scs;
  const unsigned short* bC = Wt + (size_t)jg0 * 32 * 4096 + lsrc;

  unsigned short* aL = As + w * 512;            // wave-uniform dest; HW adds lane*16B
  unsigned short* bL = Bs + w * 512;

  auto stage = [&](int k3) {                    // 4 async loads / wave / tile
    const int bu = (k3 & 1) * 8192;
#pragma unroll
    for (int p = 0; p < 2; ++p) {
      async_load16(aC + (size_t)p * 128 * Ic + k3 * 32, aL + bu + p * 4096);
      async_load16(bC + ((size_t)(p * 32 + k3)) * 4096, bL + bu + p * 4096);
    }
  };

  floatx4 acc[8][4];
#pragma unroll
  for (int tm = 0; tm < 8; ++tm)
#pragma unroll
    for (int tn = 0; tn < 4; ++tn) acc[tm][tn] = (floatx4){0.f, 0.f, 0.f, 0.f};

  const int pos = (q ^ ((lrow >> 1) & 3)) << 3;
  const unsigned short* Ard = As + ((w >> 2) << 12) + lrow * 32 + pos;
  const unsigned short* Brd = Bs + (((w >> 1) & 1) << 12) + ((w & 1) * 64 + lrow) * 32 + pos;

#define WAITVM(n) asm volatile("s_waitcnt vmcnt(" #n ")" ::: "memory")
#define CFENCE    asm volatile("" ::: "memory")

  stage(0);                                     // prime tile 0 (4 loads in flight)

  for (int kt = 0; kt < 32; ++kt) {
    // Barrier: all waves finished reading buf[(kt+1)&1] (their tile kt-1
    // reads) before any wave overwrites it with tile kt+1.
    CFENCE; __builtin_amdgcn_s_barrier(); CFENCE;
    if (kt < 31) {
      stage(kt + 1);                            // depth-1 prefetch
      WAITVM(4);                                // tile kt landed (kt+1 in flight)
    } else {
      WAITVM(0);                                // tail: only 4 outstanding — drain
    }

    const int bu = (kt & 1) * 8192;
    short8 bf[4], af0[4], af1[4];
#pragma unroll
    for (int tn = 0; tn < 4; ++tn) bf[tn] = *(const short8*)(Brd + bu + tn * 512);
#pragma unroll
    for (int i = 0; i < 4; ++i) af0[i] = *(const short8*)(Ard + bu + i * 512);
#pragma unroll
    for (int i = 0; i < 4; ++i) af1[i] = *(const short8*)(Ard + bu + (4 + i) * 512);

    __builtin_amdgcn_s_setprio(1);
#pragma unroll
    for (int i = 0; i < 4; ++i)
#pragma unroll
      for (int tn = 0; tn < 4; ++tn)
        acc[i][tn] = __builtin_amdgcn_mfma_f32_16x16x32_bf16(af0[i], bf[tn], acc[i][tn], 0, 0, 0);
#pragma unroll
    for (int i = 0; i < 4; ++i)
#pragma unroll
      for (int tn = 0; tn < 4; ++tn)
        acc[4 + i][tn] = __builtin_amdgcn_mfma_f32_16x16x32_bf16(af1[i], bf[tn], acc[4 + i][tn], 0, 0, 0);
    __builtin_amdgcn_s_setprio(0);
  }

  // epilogue: C/D layout col = lane&15, row = quad*4 + reg
  float* Yp = Y + (((size_t)(b * Ec + e) * Kc + (size_t)mt * 256) * Jc) + nt * 256;
  const int wmRow = (w >> 2) * 128;
  const int wnCol = (w & 3) * 64;
#pragma unroll
  for (int tm = 0; tm < 8; ++tm) {
#pragma unroll
    for (int tn = 0; tn < 4; ++tn) {
#pragma unroll
      for (int r = 0; r < 4; ++r) {
        const int row = wmRow + tm * 16 + q * 4 + r;
        const int col = wnCol + tn * 16 + lrow;
        Yp[(size_t)row * Jc + col] = acc[tm][tn][r];
      }
    }
  }
}

extern "C" void kernel_launch(void* const* d_in, const int* in_sizes, int n_in,
                              void* d_out, int out_size, void* d_ws, size_t ws_size,
                              hipStream_t stream) {
  const float* X = (const float*)d_in[0];
  const int* ind = (const int*)d_in[1];
  const float* W = (const float*)d_in[2];
  float* Y = (float*)d_out;

  unsigned short* Xg = (unsigned short*)d_ws;                              // 64 MiB, row-major [32768][1024]
  unsigned short* Wt = (unsigned short*)d_ws + (size_t)Bc * Ec * Kc * Ic;  // 32 MiB, chunked

  hipLaunchKernelGGL(prep, dim3(6144), dim3(256), 0, stream, X, ind, W, Xg, Wt);
  // moe_gemm decomposes blockIdx assuming exactly 512 blocks (8-XCD chunked).
  hipLaunchKernelGGL(moe_gemm, dim3(512), dim3(512), 0, stream, Xg, Wt, Y);
}

// Round 8
// 305.639 us; speedup vs baseline: 2.9178x; 2.9178x over previous
//
#include <hip/hip_runtime.h>

#define DI __device__ __forceinline__

constexpr int Bc = 4, Tc = 4096, Ic = 1024, Ec = 16, Kc = 512, Jc = 1024;

typedef __attribute__((ext_vector_type(8))) short short8;
typedef __attribute__((ext_vector_type(4))) float floatx4;

// pack two fp32 -> two bf16 (round-half-up): low16 = bf16(a), high16 = bf16(b)
DI unsigned pack2_bf16(float a, float b) {
  union { float f; unsigned u; } ua, ub;
  ua.f = a; ub.f = b;
  const unsigned x = ua.u + 0x8000u;
  const unsigned y = ub.u + 0x8000u;
#if __has_builtin(__builtin_amdgcn_perm)
  return __builtin_amdgcn_perm(y, x, 0x07060302u);
#else
  return (x >> 16) | (y & 0xFFFF0000u);
#endif
}

DI void async_load16(const void* g, void* lds) {
  __builtin_amdgcn_global_load_lds((const __attribute__((address_space(1))) void*)g,
                                   (__attribute__((address_space(3))) void*)lds,
                                   16, 0, 0);
}

// ---------------------------------------------------------------------------
// prep v5: NO gather (gather moved into moe_gemm's per-lane staging sources).
// Blocks [0,2048): pure streaming cast X f32 -> X16 bf16 row-major [B*T][I].
//   Fully coalesced both sides (float4/lane loads, 8B/lane stores), no
//   dependency chain, no scatter. 100 MB of traffic.
// Blocks [2048,4096): W transpose+cast into Wt[(e*8+jt)*32+kk][128n][32i]
//   (v3 W-part, unchanged: stride-Jc scalar loads = 256B fully-used per
//   instr, coalesced 4KB/wave stores).
__global__ __launch_bounds__(256) void prep(const float* __restrict__ X,
                                            const float* __restrict__ W,
                                            unsigned short* __restrict__ X16,
                                            unsigned short* __restrict__ Wt) {
  const int t = threadIdx.x;
  const int bx = blockIdx.x;

  if (bx < 2048) {
    // ---- X stream-cast: 16.78M floats = 4.19M float4; 8 float4/thread ----
    const int tid = bx * 256 + t;
#pragma unroll
    for (int it = 0; it < 8; ++it) {
      const size_t idx = (size_t)it * (2048 * 256) + tid;   // float4 index
      const float4 v = ((const float4*)X)[idx];
      const unsigned u0 = pack2_bf16(v.x, v.y);
      const unsigned u1 = pack2_bf16(v.z, v.w);
      const unsigned long long uu = (unsigned long long)u0 | ((unsigned long long)u1 << 32);
      *(unsigned long long*)(X16 + idx * 4) = uu;
    }
  } else {
    // ---- W part: 524,288 items = 4096 grps x 128 n ----
    const int item = (bx - 2048) * 256 + t;
    const int n   = item & 127;
    const int grp = item >> 7;          // (e*8+jt)*32 + kk
    const int kk  = grp & 31;
    const int jt  = (grp >> 5) & 7;
    const int e   = grp >> 8;
    const float* src = W + ((size_t)(e * Ic + kk * 32)) * Jc + jt * 128 + n;
    unsigned u[16];
#pragma unroll
    for (int q = 0; q < 16; ++q) {
      const float a  = src[(size_t)(2 * q) * Jc];
      const float c2 = src[(size_t)(2 * q + 1) * Jc];
      u[q] = pack2_bf16(a, c2);
    }
    unsigned short* dst = Wt + (size_t)grp * 4096 + n * 32;
#pragma unroll
    for (int q = 0; q < 4; ++q) *(uint4*)(dst + q * 8) = *(uint4*)&u[4 * q];
  }
}

// ---------------------------------------------------------------------------
// moe_gemm v4: R1's measured-best schedule (256x256 tile, BK=32, 8 waves,
// 4-deep LDS ring, counted vmcnt(8), 1 barrier/tile, launch_bounds(512,2) —
// R7 proved forcing 4 waves/EU spills the 128-reg accumulator to scratch).
// NEW: A is gathered DIRECTLY from X16 — global_load_lds's global source is
// per-lane, and the staging pattern already touches 16 scattered 64B windows
// per instruction, so ind-dependent source rows cost nothing extra. LDS bytes
// are bit-identical to the old Xg path (same cast), numerics unchanged.
// GRID MUST BE 512.
__global__ __launch_bounds__(512, 2) void moe_gemm(const unsigned short* __restrict__ X16,
                                                   const int* __restrict__ ind,
                                                   const unsigned short* __restrict__ Wt,
                                                   float* __restrict__ Y) {
  __shared__ __align__(16) unsigned short As[4 * 8192];   // 4 bufs x 16 KB
  __shared__ __align__(16) unsigned short Bs[4 * 8192];   // 4 bufs x 16 KB

  const int bid   = blockIdx.x;                 // 512 blocks
  const int lg    = (bid & 7) * 64 + (bid >> 3);
  const int e     = lg >> 5;
  const int inner = lg & 31;
  const int b     = inner >> 3;
  const int mt    = (inner >> 2) & 1;
  const int nt    = inner & 3;

  const int t = threadIdx.x;
  const int w = t >> 6;
  const int l = t & 63;
  const int lrow = l & 15;
  const int q    = l >> 4;

  const int tt0 = b * 64 + e * 4 + mt * 2;      // first 128-row tile of A
  const int jg0 = e * 8 + nt * 2;               // first 128-col Wt group

  // staging lane -> (row sr, 16B piece sc); source piece pre-swizzled so LDS
  // pos p holds data of pos p^((sr>>1)&3); read side applies the same XOR.
  const int sr = t >> 2, sc = t & 3;
  const int scs = (sc ^ ((sr >> 1) & 3)) << 3;

  // fused gather: per-lane A source rows from ind (same int32 read semantics
  // as the old prep). Rows (tt0+p)*128 + sr, p = 0,1.
  const int xr0 = ind[(tt0 + 0) * 128 + sr];
  const int xr1 = ind[(tt0 + 1) * 128 + sr];
  const unsigned short* aS0 = X16 + (((size_t)(b * Tc + xr0)) << 10) + scs;
  const unsigned short* aS1 = X16 + (((size_t)(b * Tc + xr1)) << 10) + scs;

  const size_t lsrc = (size_t)sr * 32 + scs;
  const unsigned short* bC = Wt + (size_t)jg0 * 32 * 4096 + lsrc;

  unsigned short* aL = As + w * 512;            // wave-uniform dest; HW adds lane*16B
  unsigned short* bL = Bs + w * 512;

  auto stage = [&](int k3) {                    // 4 async loads / wave / tile
    const int bu = (k3 & 3) * 8192;
    async_load16(aS0 + k3 * 32, aL + bu);
    async_load16(bC + (size_t)k3 * 4096, bL + bu);
    async_load16(aS1 + k3 * 32, aL + bu + 4096);
    async_load16(bC + ((size_t)(32 + k3)) * 4096, bL + bu + 4096);
  };

  floatx4 acc[8][4];
#pragma unroll
  for (int tm = 0; tm < 8; ++tm)
#pragma unroll
    for (int tn = 0; tn < 4; ++tn) acc[tm][tn] = (floatx4){0.f, 0.f, 0.f, 0.f};

  const int pos = (q ^ ((lrow >> 1) & 3)) << 3;
  const unsigned short* Ard = As + ((w >> 2) << 12) + lrow * 32 + pos;
  const unsigned short* Brd = Bs + (((w >> 1) & 1) << 12) + ((w & 1) * 64 + lrow) * 32 + pos;

  stage(0); stage(1); stage(2);                 // prime 3 tiles (12 loads in flight)

  auto compute = [&](int kt) {
    const int bu = (kt & 3) * 8192;
    short8 bf[4];
#pragma unroll
    for (int tn = 0; tn < 4; ++tn) bf[tn] = *(const short8*)(Brd + bu + tn * 512);
    __builtin_amdgcn_s_setprio(1);
#pragma unroll
    for (int h = 0; h < 2; ++h) {
      short8 af[4];
#pragma unroll
      for (int i2 = 0; i2 < 4; ++i2)
        af[i2] = *(const short8*)(Ard + bu + (h * 4 + i2) * 512);
#pragma unroll
      for (int i2 = 0; i2 < 4; ++i2)
#pragma unroll
        for (int tn = 0; tn < 4; ++tn)
          acc[h * 4 + i2][tn] =
              __builtin_amdgcn_mfma_f32_16x16x32_bf16(af[i2], bf[tn], acc[h * 4 + i2][tn], 0, 0, 0);
    }
    __builtin_amdgcn_s_setprio(0);
  };

#define WAITVM(n) asm volatile("s_waitcnt vmcnt(" #n ")" ::: "memory")
#define CFENCE    asm volatile("" ::: "memory")

  // steady state: tiles kt,kt+1,kt+2 in flight (12 loads); vmcnt(8) = tile kt
  // landed. Barrier => all waves' loads for kt landed AND all waves finished
  // reading kt-1, so staging kt+3 into buf[(kt+3)&3] is race-free.
#pragma unroll 4
  for (int kt = 0; kt < 28; ++kt) {
    WAITVM(8);
    CFENCE; __builtin_amdgcn_s_barrier(); CFENCE;
    stage(kt + 3);
    compute(kt);
  }
  WAITVM(8); CFENCE; __builtin_amdgcn_s_barrier(); CFENCE; stage(31); compute(28);
  WAITVM(8); CFENCE; __builtin_amdgcn_s_barrier(); CFENCE; compute(29);
  WAITVM(4); CFENCE; __builtin_amdgcn_s_barrier(); CFENCE; compute(30);
  WAITVM(0); CFENCE; __builtin_amdgcn_s_barrier(); CFENCE; compute(31);

  // epilogue: C/D layout col = lane&15, row = quad*4 + reg
  float* Yp = Y + (((size_t)(b * Ec + e) * Kc + (size_t)mt * 256) * Jc) + nt * 256;
  const int wmRow = (w >> 2) * 128;
  const int wnCol = (w & 3) * 64;
#pragma unroll
  for (int tm = 0; tm < 8; ++tm) {
#pragma unroll
    for (int tn = 0; tn < 4; ++tn) {
#pragma unroll
      for (int r = 0; r < 4; ++r) {
        const int row = wmRow + tm * 16 + q * 4 + r;
        const int col = wnCol + tn * 16 + lrow;
        Yp[(size_t)row * Jc + col] = acc[tm][tn][r];
      }
    }
  }
}

extern "C" void kernel_launch(void* const* d_in, const int* in_sizes, int n_in,
                              void* d_out, int out_size, void* d_ws, size_t ws_size,
                              hipStream_t stream) {
  const float* X = (const float*)d_in[0];
  const int* ind = (const int*)d_in[1];
  const float* W = (const float*)d_in[2];
  float* Y = (float*)d_out;

  unsigned short* X16 = (unsigned short*)d_ws;                             // 34 MiB, row-major [B*T][I]
  unsigned short* Wt  = (unsigned short*)d_ws + (size_t)Bc * Tc * Ic;      // 32 MiB, chunked

  hipLaunchKernelGGL(prep, dim3(4096), dim3(256), 0, stream, X, W, X16, Wt);
  // moe_gemm decomposes blockIdx assuming exactly 512 blocks (8-XCD chunked).
  hipLaunchKernelGGL(moe_gemm, dim3(512), dim3(512), 0, stream, X16, ind, Wt, Y);
}